// Round 4
// baseline (430.731 us; speedup 1.0000x reference)
//
#include <hip/hip_runtime.h>
#include <hip/hip_bf16.h>
#include <math.h>

typedef __bf16 bf16;
typedef __bf16 bf16x4 __attribute__((ext_vector_type(4)));
typedef __bf16 bf16x8 __attribute__((ext_vector_type(8)));
typedef float f32x4 __attribute__((ext_vector_type(4)));
typedef unsigned int u32x4 __attribute__((ext_vector_type(4)));

#define NHEADS 6
#define CDIM 192
#define IMG 56
#define NTOK 49
#define SHIFTV 3
#define XSTR 200   // padded row stride (bf16) for BufA/BufB: 400 B
#define VSTR 72    // padded stride for VT: 144 B
#define LOG2E 1.4426950408889634f
#define SCALE 0.17677669529663687f

static __device__ __forceinline__ unsigned pack2bf(float lo, float hi) {
    unsigned short a = __builtin_bit_cast(unsigned short, (bf16)lo);
    unsigned short b = __builtin_bit_cast(unsigned short, (bf16)hi);
    return (unsigned)a | ((unsigned)b << 16);
}

// ---- prep: weight transpose->bf16 + fused (bias+mask)*log2e table ----
// biasG[class c][head h][i 64][j 64], c = (wy==7)*2 + (wx==7)
__global__ void prep_weights(const float* __restrict__ w_qkv, const float* __restrict__ w_proj,
                             const float* __restrict__ rel_table,
                             bf16* __restrict__ wqkvT, bf16* __restrict__ wprojT,
                             bf16* __restrict__ biasG) {
    int i = blockIdx.x * 256 + threadIdx.x;
    if (i < 576 * 192) {
        int n = i / 192, k = i % 192;
        wqkvT[i] = (bf16)w_qkv[k * 576 + n];
    }
    if (i < 192 * 192) {
        int n = i / 192, k = i % 192;
        wprojT[i] = (bf16)w_proj[k * 192 + n];
    }
    if (i < 24 * 64 * 64) {
        int j = i & 63, ii = (i >> 6) & 63, t = i >> 12;
        int h = t % 6, c = t / 6;
        float val = -100.f;
        if (ii < 49 && j < 49) {
            int iy = ii / 7, ix = ii % 7, jy = j / 7, jx = j % 7;
            int rp = (iy - jy + 6) * 13 + (ix - jx + 6);
            bool ym = !(c & 2) || ((iy < 4) == (jy < 4));
            bool xm = !(c & 1) || ((ix < 4) == (jx < 4));
            val = rel_table[rp * 6 + h] + ((ym && xm) ? 0.f : -100.f);
        }
        biasG[i] = (bf16)(val * LOG2E);
    }
}

__global__ __launch_bounds__(512, 4) void swin_block(
    const float* __restrict__ x, const float* __restrict__ gamma, const float* __restrict__ beta,
    const bf16* __restrict__ wqkvT, const float* __restrict__ b_qkv,
    const bf16* __restrict__ biasG, const bf16* __restrict__ wprojT,
    const float* __restrict__ b_proj, float* __restrict__ out)
{
    __shared__ __align__(16) bf16 BufA[64 * XSTR];     // X (ph0-1), then K (in place)
    __shared__ __align__(16) bf16 BufB[64 * XSTR];     // Q (ph1-2), then O in place (ph2-3)
    __shared__ __align__(16) bf16 VTs[CDIM * VSTR];    // V transposed: [channel][token]
    // total 78848 B -> 2 blocks/CU

    const int blk  = blockIdx.x;
    const int bimg = blk >> 6;
    const int wy   = (blk >> 3) & 7;
    const int wx   = blk & 7;
    const int tid  = threadIdx.x;
    const int wave = tid >> 6;   // 0..7
    const int lane = tid & 63;

    // ---- phase 0: shifted-window load + LayerNorm -> BufA (bf16), rows 49..63 zero ----
    {
        const float g0 = gamma[lane], g1 = gamma[lane + 64], g2 = gamma[lane + 128];
        const float b0 = beta[lane],  b1 = beta[lane + 64],  b2 = beta[lane + 128];
        for (int t = wave; t < 64; t += 8) {
            if (t < NTOK) {
                int ty = t / 7, tx = t % 7;
                int oy = wy * 7 + ty + SHIFTV; if (oy >= IMG) oy -= IMG;
                int ox = wx * 7 + tx + SHIFTV; if (ox >= IMG) ox -= IMG;
                const float* xp = x + (((size_t)bimg * IMG + oy) * IMG + ox) * CDIM;
                float v0 = xp[lane], v1 = xp[lane + 64], v2 = xp[lane + 128];
                float s = v0 + v1 + v2, ss = v0 * v0 + v1 * v1 + v2 * v2;
                #pragma unroll
                for (int off = 32; off; off >>= 1) { s += __shfl_xor(s, off); ss += __shfl_xor(ss, off); }
                float mu  = s * (1.f / 192.f);
                float var = ss * (1.f / 192.f) - mu * mu;
                float rs  = rsqrtf(var + 1e-5f);
                BufA[t * XSTR + lane      ] = (bf16)((v0 - mu) * rs * g0 + b0);
                BufA[t * XSTR + lane + 64 ] = (bf16)((v1 - mu) * rs * g1 + b1);
                BufA[t * XSTR + lane + 128] = (bf16)((v2 - mu) * rs * g2 + b2);
            } else {
                BufA[t * XSTR + lane      ] = (bf16)0.f;
                BufA[t * XSTR + lane + 64 ] = (bf16)0.f;
                BufA[t * XSTR + lane + 128] = (bf16)0.f;
            }
        }
    }
    __syncthreads();

    // ---- phase 1: QKV = X @ Wqkv + b. Wave = row-half (w&1) x col-group (w>>1), 9 tiles ----
    {
        const int lr = lane & 15, lq = lane >> 4;
        const int h0 = wave & 1;       // token half
        const int cg = wave >> 1;      // col-group 0..3
        bf16x8 afrag[2][6];
        #pragma unroll
        for (int mm = 0; mm < 2; ++mm)
            #pragma unroll
            for (int k = 0; k < 6; ++k)
                afrag[mm][k] = *(const bf16x8*)&BufA[(32 * h0 + 16 * mm + lr) * XSTR + k * 32 + lq * 8];
        __syncthreads();   // all waves cached X before K overwrites BufA

        for (int t = 0; t < 9; ++t) {
            const int nt = cg + 4 * t;
            const bf16* wp = wqkvT + (size_t)(nt * 16 + lr) * CDIM + lq * 8;
            bf16x8 bfrag[6];
            #pragma unroll
            for (int k = 0; k < 6; ++k) bfrag[k] = *(const bf16x8*)(wp + k * 32);
            const int sect = nt / 12;   // wave-uniform
            f32x4 acc[2];
            acc[0] = f32x4{0.f, 0.f, 0.f, 0.f}; acc[1] = f32x4{0.f, 0.f, 0.f, 0.f};
            if (sect == 2) {
                // V: unswapped -> D: channel = nt*16+lr (li), token = 32h0+16mm+4lq+r (packed)
                #pragma unroll
                for (int k = 0; k < 6; ++k)
                    #pragma unroll
                    for (int mm = 0; mm < 2; ++mm)
                        acc[mm] = __builtin_amdgcn_mfma_f32_16x16x32_bf16(afrag[mm][k], bfrag[k], acc[mm], 0, 0, 0);
                const int cc   = (nt - 24) * 16 + lr;
                const float bb = b_qkv[384 + cc];
                #pragma unroll
                for (int mm = 0; mm < 2; ++mm) {
                    bf16x4 v4;
                    #pragma unroll
                    for (int r = 0; r < 4; ++r) v4[r] = (bf16)(acc[mm][r] + bb);
                    *(bf16x4*)&VTs[cc * VSTR + 32 * h0 + 16 * mm + 4 * lq] = v4;
                }
            } else {
                // Q/K: swapped -> D: token = 32h0+16mm+lr (li), channel = nt*16+4lq+r (packed)
                #pragma unroll
                for (int k = 0; k < 6; ++k)
                    #pragma unroll
                    for (int mm = 0; mm < 2; ++mm)
                        acc[mm] = __builtin_amdgcn_mfma_f32_16x16x32_bf16(bfrag[k], afrag[mm][k], acc[mm], 0, 0, 0);
                const int col0 = nt * 16 + 4 * lq;
                const f32x4 bq4 = *(const f32x4*)&b_qkv[col0];
                const int ccl  = (nt % 12) * 16 + 4 * lq;
                bf16* dst = sect ? BufA : BufB;
                #pragma unroll
                for (int mm = 0; mm < 2; ++mm) {
                    bf16x4 v4;
                    #pragma unroll
                    for (int r = 0; r < 4; ++r) v4[r] = (bf16)(acc[mm][r] + bq4[r]);
                    *(bf16x4*)&dst[(32 * h0 + 16 * mm + lr) * XSTR + ccl] = v4;
                }
            }
        }
    }
    __syncthreads();

    // ---- phase 2: attention, swapped QK^T (S^T), table bias, in-register P^T, barrier-free ----
    {
        const int li = lane & 15, lq = lane >> 4;
        const int m  = wave & 3;
        const int hg = wave >> 2;
        const int cls = ((wy == 7) ? 2 : 0) | ((wx == 7) ? 1 : 0);
        const bf16* bgp = biasG + (((size_t)cls * 6 + hg * 3) * 64 + (16 * m + li)) * 64 + 4 * lq;
        const int src0 = li + 32 * (lq & 1);
        const float SC = SCALE * LOG2E;

        #pragma unroll
        for (int hh = 0; hh < 3; ++hh) {
            const int h = hg * 3 + hh;
            bf16x8 bq = *(const bf16x8*)&BufB[(16 * m + li) * XSTR + h * 32 + lq * 8];
            f32x4 st[4];
            #pragma unroll
            for (int n = 0; n < 4; ++n) {
                bf16x8 ak = *(const bf16x8*)&BufA[(16 * n + li) * XSTR + h * 32 + lq * 8];
                st[n] = __builtin_amdgcn_mfma_f32_16x16x32_bf16(ak, bq, f32x4{0.f, 0.f, 0.f, 0.f}, 0, 0, 0);
            }
            bf16x4 b4[4];
            #pragma unroll
            for (int n = 0; n < 4; ++n) b4[n] = *(const bf16x4*)(bgp + hh * 4096 + 16 * n);
            // u = (s*scale + bias + mask) * log2e ; j = 16n + 4lq + r
            float p[4][4];
            float umax = -1e30f;
            #pragma unroll
            for (int n = 0; n < 4; ++n)
                #pragma unroll
                for (int r = 0; r < 4; ++r) {
                    float v = fmaf(st[n][r], SC, (float)b4[n][r]);
                    p[n][r] = v;
                    umax = fmaxf(umax, v);
                }
            umax = fmaxf(umax, __shfl_xor(umax, 16));
            umax = fmaxf(umax, __shfl_xor(umax, 32));
            float sum = 0.f;
            #pragma unroll
            for (int n = 0; n < 4; ++n)
                #pragma unroll
                for (int r = 0; r < 4; ++r) {
                    float e = exp2f(p[n][r] - umax);
                    p[n][r] = e; sum += e;
                }
            sum += __shfl_xor(sum, 16);
            sum += __shfl_xor(sum, 32);
            const float inv = 1.f / sum;
            unsigned pk[4][2];
            #pragma unroll
            for (int n = 0; n < 4; ++n)
                #pragma unroll
                for (int s = 0; s < 2; ++s)
                    pk[n][s] = pack2bf(p[n][2 * s] * inv, p[n][2 * s + 1] * inv);
            // shuffle D-layout -> B-frag(P^T)
            u32x4 ptw0, ptw1;
            #pragma unroll
            for (int w = 0; w < 4; ++w) {
                int srcl = src0 + 16 * (w >> 1);
                int s = w & 1;
                unsigned a0 = (unsigned)__shfl((int)pk[0][s], srcl);
                unsigned b0 = (unsigned)__shfl((int)pk[1][s], srcl);
                unsigned a1 = (unsigned)__shfl((int)pk[2][s], srcl);
                unsigned b1 = (unsigned)__shfl((int)pk[3][s], srcl);
                ptw0[w] = (lq & 2) ? b0 : a0;
                ptw1[w] = (lq & 2) ? b1 : a1;
            }
            bf16x8 bp0 = __builtin_bit_cast(bf16x8, ptw0);
            bf16x8 bp1 = __builtin_bit_cast(bf16x8, ptw1);
            // PV: O^T = V^T · P^T
            f32x4 ot[2];
            #pragma unroll
            for (int dt = 0; dt < 2; ++dt) {
                const bf16* vrow = &VTs[(h * 32 + 16 * dt + li) * VSTR + lq * 8];
                bf16x8 av0 = *(const bf16x8*)(vrow);
                bf16x8 av1 = *(const bf16x8*)(vrow + 32);
                ot[dt] = __builtin_amdgcn_mfma_f32_16x16x32_bf16(av0, bp0, f32x4{0.f, 0.f, 0.f, 0.f}, 0, 0, 0);
                ot[dt] = __builtin_amdgcn_mfma_f32_16x16x32_bf16(av1, bp1, ot[dt], 0, 0, 0);
            }
            #pragma unroll
            for (int dt = 0; dt < 2; ++dt) {
                bf16x4 o4;
                #pragma unroll
                for (int r = 0; r < 4; ++r) o4[r] = (bf16)ot[dt][r];
                *(bf16x4*)&BufB[(16 * m + li) * XSTR + h * 32 + 16 * dt + 4 * lq] = o4;
            }
        }
    }
    __syncthreads();

    // ---- phase 3: proj + bias, swapped -> packed dwordx4 stores; wave = (tg = w&3, ch2 = w>>2) ----
    {
        const int li = lane & 15, lq = lane >> 4;
        const int tg  = wave & 3;
        const int ch2 = wave >> 2;
        bf16x8 ofrag[6];
        #pragma unroll
        for (int k = 0; k < 6; ++k)
            ofrag[k] = *(const bf16x8*)&BufB[(16 * tg + li) * XSTR + k * 32 + lq * 8];
        const int row = 16 * tg + li;
        const bool valid = row < NTOK;
        int ty = row / 7, tx = row % 7;
        int oy = wy * 7 + ty + SHIFTV; if (oy >= IMG) oy -= IMG;
        int ox = wx * 7 + tx + SHIFTV; if (ox >= IMG) ox -= IMG;
        float* orow = out + (((size_t)bimg * IMG + oy) * IMG + ox) * CDIM;

        for (int s3 = 0; s3 < 6; ++s3) {
            const int nt = ch2 * 6 + s3;
            const bf16* wp = wprojT + (size_t)(nt * 16 + li) * CDIM + lq * 8;
            bf16x8 wfrag[6];
            #pragma unroll
            for (int k = 0; k < 6; ++k) wfrag[k] = *(const bf16x8*)(wp + k * 32);
            f32x4 acc = f32x4{0.f, 0.f, 0.f, 0.f};
            #pragma unroll
            for (int k = 0; k < 6; ++k)
                acc = __builtin_amdgcn_mfma_f32_16x16x32_bf16(wfrag[k], ofrag[k], acc, 0, 0, 0);
            const int c0 = nt * 16 + 4 * lq;
            const f32x4 bp = *(const f32x4*)&b_proj[c0];
            if (valid) {
                f32x4 v;
                #pragma unroll
                for (int r = 0; r < 4; ++r) v[r] = acc[r] + bp[r];
                *(f32x4*)&orow[c0] = v;
            }
        }
    }
}

extern "C" void kernel_launch(void* const* d_in, const int* in_sizes, int n_in,
                              void* d_out, int out_size, void* d_ws, size_t ws_size,
                              hipStream_t stream) {
    const float* x           = (const float*)d_in[0];
    const float* gamma       = (const float*)d_in[1];
    const float* beta        = (const float*)d_in[2];
    const float* w_qkv       = (const float*)d_in[3];
    const float* b_qkv       = (const float*)d_in[4];
    const float* rel_table   = (const float*)d_in[5];
    const float* w_proj      = (const float*)d_in[6];
    const float* b_proj      = (const float*)d_in[7];
    // d_in[8] = mask_matrix: folded into biasG table
    float* out = (float*)d_out;

    bf16* wqkvT  = (bf16*)d_ws;                                    // 221184 B
    bf16* wprojT = (bf16*)((char*)d_ws + 221184);                  //  73728 B
    bf16* biasG  = (bf16*)((char*)d_ws + 221184 + 73728);          // 196608 B

    prep_weights<<<432, 256, 0, stream>>>(w_qkv, w_proj, rel_table, wqkvT, wprojT, biasG);
    swin_block<<<4096, 512, 0, stream>>>(x, gamma, beta, wqkvT, b_qkv, biasG,
                                         wprojT, b_proj, out);
}

// Round 5
// 361.513 us; speedup vs baseline: 1.1915x; 1.1915x over previous
//
#include <hip/hip_runtime.h>
#include <hip/hip_bf16.h>
#include <math.h>

typedef __bf16 bf16;
typedef __bf16 bf16x4 __attribute__((ext_vector_type(4)));
typedef __bf16 bf16x8 __attribute__((ext_vector_type(8)));
typedef float f32x4 __attribute__((ext_vector_type(4)));
typedef unsigned int u32x4 __attribute__((ext_vector_type(4)));

#define NHEADS 6
#define CDIM 192
#define IMG 56
#define NTOK 49
#define SHIFTV 3
#define XSTR 200   // padded row stride (bf16) for BufA/BufB: 400 B
#define VSTR 72    // padded stride for VT: 144 B
#define LOG2E 1.4426950408889634f
#define SCALE 0.17677669529663687f
#define MSKNEG (-100.0f * LOG2E)

static __device__ __forceinline__ unsigned pack2bf(float lo, float hi) {
    unsigned short a = __builtin_bit_cast(unsigned short, (bf16)lo);
    unsigned short b = __builtin_bit_cast(unsigned short, (bf16)hi);
    return (unsigned)a | ((unsigned)b << 16);
}

// ---- weight prep: fp32 -> bf16, transposed to [N][K] so B-fragments are contiguous ----
__global__ void prep_weights(const float* __restrict__ w_qkv, const float* __restrict__ w_proj,
                             bf16* __restrict__ wqkvT, bf16* __restrict__ wprojT) {
    int i = blockIdx.x * 256 + threadIdx.x;
    if (i < 576 * 192) {
        int n = i / 192, k = i % 192;
        wqkvT[i] = (bf16)w_qkv[k * 576 + n];
    }
    if (i < 192 * 192) {
        int n = i / 192, k = i % 192;
        wprojT[i] = (bf16)w_proj[k * 192 + n];
    }
}

__global__ __launch_bounds__(512, 4) void swin_block(
    const float* __restrict__ x, const float* __restrict__ gamma, const float* __restrict__ beta,
    const bf16* __restrict__ wqkvT, const float* __restrict__ b_qkv,
    const float* __restrict__ rel_table, const bf16* __restrict__ wprojT,
    const float* __restrict__ b_proj, float* __restrict__ out)
{
    __shared__ __align__(16) bf16 BufA[64 * XSTR];     // X (ph0-1), then K (in place)
    __shared__ __align__(16) bf16 BufB[64 * XSTR];     // Q (ph1-2), then O in place (ph2-3)
    __shared__ __align__(16) bf16 VTs[CDIM * VSTR];    // V transposed: [channel][token]
    __shared__ bf16 biasS[169 * NHEADS];               // rel-pos bias * log2e, bf16

    const int blk  = blockIdx.x;
    const int bimg = blk >> 6;
    const int wy   = (blk >> 3) & 7;
    const int wx   = blk & 7;
    const int tid  = threadIdx.x;
    const int wave = tid >> 6;   // 0..7
    const int lane = tid & 63;

    for (int i = tid; i < 169 * NHEADS; i += 512) biasS[i] = (bf16)(rel_table[i] * LOG2E);

    // ---- phase 0: shifted-window load + LayerNorm -> BufA (bf16), rows 49..63 zero ----
    {
        const float g0 = gamma[lane], g1 = gamma[lane + 64], g2 = gamma[lane + 128];
        const float b0 = beta[lane],  b1 = beta[lane + 64],  b2 = beta[lane + 128];
        for (int t = wave; t < 64; t += 8) {
            if (t < NTOK) {
                int ty = t / 7, tx = t % 7;
                int oy = wy * 7 + ty + SHIFTV; if (oy >= IMG) oy -= IMG;
                int ox = wx * 7 + tx + SHIFTV; if (ox >= IMG) ox -= IMG;
                const float* xp = x + (((size_t)bimg * IMG + oy) * IMG + ox) * CDIM;
                float v0 = xp[lane], v1 = xp[lane + 64], v2 = xp[lane + 128];
                float s = v0 + v1 + v2, ss = v0 * v0 + v1 * v1 + v2 * v2;
                #pragma unroll
                for (int off = 32; off; off >>= 1) { s += __shfl_xor(s, off); ss += __shfl_xor(ss, off); }
                float mu  = s * (1.f / 192.f);
                float var = ss * (1.f / 192.f) - mu * mu;
                float rs  = rsqrtf(var + 1e-5f);
                BufA[t * XSTR + lane      ] = (bf16)((v0 - mu) * rs * g0 + b0);
                BufA[t * XSTR + lane + 64 ] = (bf16)((v1 - mu) * rs * g1 + b1);
                BufA[t * XSTR + lane + 128] = (bf16)((v2 - mu) * rs * g2 + b2);
            } else {
                BufA[t * XSTR + lane      ] = (bf16)0.f;
                BufA[t * XSTR + lane + 64 ] = (bf16)0.f;
                BufA[t * XSTR + lane + 128] = (bf16)0.f;
            }
        }
    }
    __syncthreads();

    // ---- phase 1: QKV = X @ Wqkv + b. Wave = token-half (w&1) x col-group (w>>1), 9 tiles ----
    {
        const int lr = lane & 15, lq = lane >> 4;
        const int h0 = wave & 1;
        const int cg = wave >> 1;
        bf16x8 afrag[2][6];
        #pragma unroll
        for (int mm = 0; mm < 2; ++mm)
            #pragma unroll
            for (int k = 0; k < 6; ++k)
                afrag[mm][k] = *(const bf16x8*)&BufA[(32 * h0 + 16 * mm + lr) * XSTR + k * 32 + lq * 8];
        __syncthreads();   // all waves cached X before K overwrites BufA

        for (int t = 0; t < 9; ++t) {
            const int nt = cg + 4 * t;
            const bf16* wp = wqkvT + (size_t)(nt * 16 + lr) * CDIM + lq * 8;
            bf16x8 bfrag[6];
            #pragma unroll
            for (int k = 0; k < 6; ++k) bfrag[k] = *(const bf16x8*)(wp + k * 32);
            const int sect = nt / 12;   // wave-uniform
            f32x4 acc[2];
            acc[0] = f32x4{0.f, 0.f, 0.f, 0.f}; acc[1] = f32x4{0.f, 0.f, 0.f, 0.f};
            if (sect == 2) {
                // V: unswapped -> D: channel = nt*16+lr, token = 32h0+16mm+4lq+r (packed)
                #pragma unroll
                for (int k = 0; k < 6; ++k)
                    #pragma unroll
                    for (int mm = 0; mm < 2; ++mm)
                        acc[mm] = __builtin_amdgcn_mfma_f32_16x16x32_bf16(afrag[mm][k], bfrag[k], acc[mm], 0, 0, 0);
                const int cc   = (nt - 24) * 16 + lr;
                const float bb = b_qkv[384 + cc];
                #pragma unroll
                for (int mm = 0; mm < 2; ++mm) {
                    bf16x4 v4;
                    #pragma unroll
                    for (int r = 0; r < 4; ++r) v4[r] = (bf16)(acc[mm][r] + bb);
                    *(bf16x4*)&VTs[cc * VSTR + 32 * h0 + 16 * mm + 4 * lq] = v4;
                }
            } else {
                // Q/K: swapped -> D: token = 32h0+16mm+lr, channel = nt*16+4lq+r (packed)
                #pragma unroll
                for (int k = 0; k < 6; ++k)
                    #pragma unroll
                    for (int mm = 0; mm < 2; ++mm)
                        acc[mm] = __builtin_amdgcn_mfma_f32_16x16x32_bf16(bfrag[k], afrag[mm][k], acc[mm], 0, 0, 0);
                const int col0 = nt * 16 + 4 * lq;
                const f32x4 bq4 = *(const f32x4*)&b_qkv[col0];
                const int ccl  = (nt % 12) * 16 + 4 * lq;
                bf16* dst = sect ? BufA : BufB;
                #pragma unroll
                for (int mm = 0; mm < 2; ++mm) {
                    bf16x4 v4;
                    #pragma unroll
                    for (int r = 0; r < 4; ++r) v4[r] = (bf16)(acc[mm][r] + bq4[r]);
                    *(bf16x4*)&dst[(32 * h0 + 16 * mm + lr) * XSTR + ccl] = v4;
                }
            }
        }
    }
    __syncthreads();

    // ---- phase 2: attention, swapped QK^T (S^T), LDS bias, in-register P^T, 3 heads unrolled ----
    {
        const int li = lane & 15, lq = lane >> 4;
        const int m  = wave & 3;
        const int hg = wave >> 2;
        const int i  = 16 * m + li;
        const int ic = i < NTOK ? i : NTOK - 1;
        const int iy = ic / 7, ix = ic % 7;
        const int ay = wy * 7 + iy, ax = wx * 7 + ix;
        const int ryi = (ay < 49) ? 0 : ((ay < 53) ? 1 : 2);
        const int rxi = (ax < 49) ? 0 : ((ax < 53) ? 1 : 2);
        int   rp[4][4];
        float msk[4][4];
        #pragma unroll
        for (int n = 0; n < 4; ++n)
            #pragma unroll
            for (int r = 0; r < 4; ++r) {
                int j = 16 * n + 4 * lq + r;
                if (j < NTOK) {
                    int jy = j / 7, jx = j % 7;
                    rp[n][r] = ((iy - jy + 6) * 13 + (ix - jx + 6)) * NHEADS;
                    int by = wy * 7 + jy, bx = wx * 7 + jx;
                    int ryj = (by < 49) ? 0 : ((by < 53) ? 1 : 2);
                    int rxj = (bx < 49) ? 0 : ((bx < 53) ? 1 : 2);
                    msk[n][r] = (ryi == ryj && rxi == rxj) ? 0.f : MSKNEG;
                } else { rp[n][r] = 0; msk[n][r] = -1e30f; }
            }
        const int src0 = li + 32 * (lq & 1);
        const float SC = SCALE * LOG2E;

        #pragma unroll
        for (int hh = 0; hh < 3; ++hh) {
            const int h = hg * 3 + hh;
            bf16x8 bq = *(const bf16x8*)&BufB[(16 * m + li) * XSTR + h * 32 + lq * 8];
            f32x4 st[4];
            #pragma unroll
            for (int n = 0; n < 4; ++n) {
                bf16x8 ak = *(const bf16x8*)&BufA[(16 * n + li) * XSTR + h * 32 + lq * 8];
                st[n] = __builtin_amdgcn_mfma_f32_16x16x32_bf16(ak, bq, f32x4{0.f, 0.f, 0.f, 0.f}, 0, 0, 0);
            }
            // u = st*scale*log2e + bias*log2e + msk ; j = 16n + 4lq + r
            float p[4][4];
            float umax = -1e30f;
            #pragma unroll
            for (int n = 0; n < 4; ++n)
                #pragma unroll
                for (int r = 0; r < 4; ++r) {
                    float v = fmaf(st[n][r], SC, msk[n][r]) + (float)biasS[rp[n][r] + h];
                    p[n][r] = v;
                    umax = fmaxf(umax, v);
                }
            umax = fmaxf(umax, __shfl_xor(umax, 16));
            umax = fmaxf(umax, __shfl_xor(umax, 32));
            float sum = 0.f;
            #pragma unroll
            for (int n = 0; n < 4; ++n)
                #pragma unroll
                for (int r = 0; r < 4; ++r) {
                    float e = exp2f(p[n][r] - umax);
                    p[n][r] = e; sum += e;
                }
            sum += __shfl_xor(sum, 16);
            sum += __shfl_xor(sum, 32);
            const float inv = 1.f / sum;
            unsigned pk[4][2];
            #pragma unroll
            for (int n = 0; n < 4; ++n)
                #pragma unroll
                for (int s = 0; s < 2; ++s)
                    pk[n][s] = pack2bf(p[n][2 * s] * inv, p[n][2 * s + 1] * inv);
            // shuffle D-layout -> B-frag(P^T)
            u32x4 ptw0, ptw1;
            #pragma unroll
            for (int w = 0; w < 4; ++w) {
                int srcl = src0 + 16 * (w >> 1);
                int s = w & 1;
                unsigned a0 = (unsigned)__shfl((int)pk[0][s], srcl);
                unsigned b0 = (unsigned)__shfl((int)pk[1][s], srcl);
                unsigned a1 = (unsigned)__shfl((int)pk[2][s], srcl);
                unsigned b1 = (unsigned)__shfl((int)pk[3][s], srcl);
                ptw0[w] = (lq & 2) ? b0 : a0;
                ptw1[w] = (lq & 2) ? b1 : a1;
            }
            bf16x8 bp0 = __builtin_bit_cast(bf16x8, ptw0);
            bf16x8 bp1 = __builtin_bit_cast(bf16x8, ptw1);
            // PV: O^T = V^T · P^T
            f32x4 ot[2];
            #pragma unroll
            for (int dt = 0; dt < 2; ++dt) {
                const bf16* vrow = &VTs[(h * 32 + 16 * dt + li) * VSTR + lq * 8];
                bf16x8 av0 = *(const bf16x8*)(vrow);
                bf16x8 av1 = *(const bf16x8*)(vrow + 32);
                ot[dt] = __builtin_amdgcn_mfma_f32_16x16x32_bf16(av0, bp0, f32x4{0.f, 0.f, 0.f, 0.f}, 0, 0, 0);
                ot[dt] = __builtin_amdgcn_mfma_f32_16x16x32_bf16(av1, bp1, ot[dt], 0, 0, 0);
            }
            #pragma unroll
            for (int dt = 0; dt < 2; ++dt) {
                bf16x4 o4;
                #pragma unroll
                for (int r = 0; r < 4; ++r) o4[r] = (bf16)ot[dt][r];
                *(bf16x4*)&BufB[(16 * m + li) * XSTR + h * 32 + 16 * dt + 4 * lq] = o4;
            }
        }
    }
    __syncthreads();

    // ---- phase 3: proj + bias, swapped, dual-acc; wave = (half = w&1, cg = w>>1), 3 units ----
    {
        const int li = lane & 15, lq = lane >> 4;
        const int half = wave & 1;
        const int cg   = wave >> 1;
        bf16x8 ofrag[2][6];
        #pragma unroll
        for (int mm = 0; mm < 2; ++mm)
            #pragma unroll
            for (int k = 0; k < 6; ++k)
                ofrag[mm][k] = *(const bf16x8*)&BufB[(32 * half + 16 * mm + li) * XSTR + k * 32 + lq * 8];
        float* orow[2];
        bool   valid[2];
        #pragma unroll
        for (int mm = 0; mm < 2; ++mm) {
            const int row = 32 * half + 16 * mm + li;
            valid[mm] = row < NTOK;
            int rr = valid[mm] ? row : 0;
            int ty = rr / 7, tx = rr % 7;
            int oy = wy * 7 + ty + SHIFTV; if (oy >= IMG) oy -= IMG;
            int ox = wx * 7 + tx + SHIFTV; if (ox >= IMG) ox -= IMG;
            orow[mm] = out + (((size_t)bimg * IMG + oy) * IMG + ox) * CDIM;
        }

        for (int s3 = 0; s3 < 3; ++s3) {
            const int nt = cg + 4 * s3;
            const bf16* wp = wprojT + (size_t)(nt * 16 + li) * CDIM + lq * 8;
            bf16x8 wfrag[6];
            #pragma unroll
            for (int k = 0; k < 6; ++k) wfrag[k] = *(const bf16x8*)(wp + k * 32);
            f32x4 acc[2];
            acc[0] = f32x4{0.f, 0.f, 0.f, 0.f}; acc[1] = f32x4{0.f, 0.f, 0.f, 0.f};
            #pragma unroll
            for (int k = 0; k < 6; ++k)
                #pragma unroll
                for (int mm = 0; mm < 2; ++mm)
                    acc[mm] = __builtin_amdgcn_mfma_f32_16x16x32_bf16(wfrag[k], ofrag[mm][k], acc[mm], 0, 0, 0);
            const int c0 = nt * 16 + 4 * lq;
            const f32x4 bp = *(const f32x4*)&b_proj[c0];
            #pragma unroll
            for (int mm = 0; mm < 2; ++mm) {
                if (valid[mm]) {
                    f32x4 v;
                    #pragma unroll
                    for (int r = 0; r < 4; ++r) v[r] = acc[mm][r] + bp[r];
                    *(f32x4*)&orow[mm][c0] = v;
                }
            }
        }
    }
}

extern "C" void kernel_launch(void* const* d_in, const int* in_sizes, int n_in,
                              void* d_out, int out_size, void* d_ws, size_t ws_size,
                              hipStream_t stream) {
    const float* x           = (const float*)d_in[0];
    const float* gamma       = (const float*)d_in[1];
    const float* beta        = (const float*)d_in[2];
    const float* w_qkv       = (const float*)d_in[3];
    const float* b_qkv       = (const float*)d_in[4];
    const float* rel_table   = (const float*)d_in[5];
    const float* w_proj      = (const float*)d_in[6];
    const float* b_proj      = (const float*)d_in[7];
    // d_in[8] = mask_matrix: recomputed inline from window coords
    float* out = (float*)d_out;

    bf16* wqkvT  = (bf16*)d_ws;
    bf16* wprojT = (bf16*)((char*)d_ws + (size_t)576 * 192 * 2);

    prep_weights<<<432, 256, 0, stream>>>(w_qkv, w_proj, wqkvT, wprojT);
    swin_block<<<4096, 512, 0, stream>>>(x, gamma, beta, wqkvT, b_qkv, rel_table,
                                         wprojT, b_proj, out);
}